// Round 4
// baseline (333.436 us; speedup 1.0000x reference)
//
#include <hip/hip_runtime.h>
#include <hip/hip_bf16.h>

// SimCLR NT-Xent loss. B=4096, D=256, N=2B=8192 rows.
// loss = (1/N) sum_i [ log(denom_i) - log(pos_i) ]
//   denom_i = sum_{j!=i} exp(2*sim_ij),  pos_i = cos(z_i, z_{i+-B}) (fp32 path)
//
// denom: fp8(e4m3) sim-GEMM via mfma_scale_f32_16x16x128_f8f6f4 (unit scales,
// numerics verified R3: absmax 0.0). R4 fixes R3's register spill (293 MB
// scratch writes): A-frags are short-lived direct global->VGPR i32x8 loads,
// B-frags held only 2-nt at a time (32 VGPRs), K=256 in one MFMA pair.

#define NROWS 8192
#define BHALF 4096
#define DDIM  256
#define JITERS 2

typedef __attribute__((ext_vector_type(4))) int   i32x4;
typedef __attribute__((ext_vector_type(8))) int   i32x8;
typedef __attribute__((ext_vector_type(4))) float f32x4;

#define SCALE1 0x7F7F7F7F   // e8m0 biased-127 = 2^0 in every byte

__device__ __forceinline__ void load_lds16(const unsigned char* g, unsigned char* l) {
    __builtin_amdgcn_global_load_lds(
        (const __attribute__((address_space(1))) void*)g,
        (__attribute__((address_space(3))) void*)l, 16, 0, 0);
}

// Kernel 1: norms + fp8-normalized matrix + positive-pair log partials + denom=0.
__global__ __launch_bounds__(256) void prep_kernel(const float* __restrict__ z1,
                                                   const float* __restrict__ z2,
                                                   unsigned char* __restrict__ zn8,
                                                   float* __restrict__ posPart,
                                                   float* __restrict__ denom) {
    __shared__ float sp[4];
    int wave = threadIdx.x >> 6;
    int lane = threadIdx.x & 63;
    int i    = blockIdx.x * 4 + wave;
    float4 a = reinterpret_cast<const float4*>(z1 + (size_t)i * DDIM)[lane];
    float4 b = reinterpret_cast<const float4*>(z2 + (size_t)i * DDIM)[lane];
    float ss1 = a.x * a.x + a.y * a.y + a.z * a.z + a.w * a.w;
    float ss2 = b.x * b.x + b.y * b.y + b.z * b.z + b.w * b.w;
    float dd  = a.x * b.x + a.y * b.y + a.z * b.z + a.w * b.w;
    #pragma unroll
    for (int off = 32; off; off >>= 1) {
        ss1 += __shfl_xor(ss1, off);
        ss2 += __shfl_xor(ss2, off);
        dd  += __shfl_xor(dd, off);
    }
    float n1 = fmaxf(sqrtf(ss1), 1e-8f);
    float n2 = fmaxf(sqrtf(ss2), 1e-8f);
    float i1 = 1.0f / n1, i2 = 1.0f / n2;
    int pa = __builtin_amdgcn_cvt_pk_fp8_f32(a.x * i1, a.y * i1, 0, 0);
    pa     = __builtin_amdgcn_cvt_pk_fp8_f32(a.z * i1, a.w * i1, pa, 1);
    int pb = __builtin_amdgcn_cvt_pk_fp8_f32(b.x * i2, b.y * i2, 0, 0);
    pb     = __builtin_amdgcn_cvt_pk_fp8_f32(b.z * i2, b.w * i2, pb, 1);
    reinterpret_cast<int*>(zn8 + (size_t)i * DDIM)[lane] = pa;
    reinterpret_cast<int*>(zn8 + (size_t)(i + BHALF) * DDIM)[lane] = pb;
    if (lane == 0) sp[wave] = __logf(dd * i1 * i2);
    if (threadIdx.x < 8) denom[blockIdx.x * 8 + threadIdx.x] = 0.0f;
    __syncthreads();
    if (threadIdx.x == 0)
        posPart[blockIdx.x] = sp[0] + sp[1] + sp[2] + sp[3];
}

// Kernel 2: fp8 MFMA sim-GEMM + exp row-sum. 128-i x (128*JITERS)-j per block,
// waves 2x2, K=256 in one scaled-MFMA pair. B via LDS (R3 swizzle, 0
// conflicts); A direct global->VGPR per mt (L1-resident, short-lived).
__global__ __launch_bounds__(256, 4) void denom_kernel(const unsigned char* __restrict__ zn8,
                                                       float* __restrict__ denom) {
    __shared__ __align__(16) unsigned char sB[128 * DDIM];   // 32 KB

    int t    = threadIdx.x;
    int lane = t & 63;
    int wave = t >> 6;
    int col  = lane & 15;
    int quad = lane >> 4;
    int wm = wave >> 1, wn = wave & 1;
    int iBase  = blockIdx.y * 128;
    int jBase0 = blockIdx.x * (128 * JITERS);

    // staging (16-B granules, chunk = pos ^ (row&15)): verified R3.
    int rowInWave = wave * 4 + quad;
    int swz = col ^ rowInWave;
    const unsigned char* gB = zn8 + (size_t)(jBase0 + rowInWave) * DDIM + swz * 16;
    unsigned char* lB = sB + wave * 1024 + lane * 16;

    // B fragment granule offsets: pos = (ks*8 + quad*2 + b) ^ col.
    int po[4];
    #pragma unroll
    for (int ks = 0; ks < 2; ks++)
        #pragma unroll
        for (int b = 0; b < 2; b++)
            po[ks * 2 + b] = ((ks * 8 + quad * 2 + b) ^ col) * 16;
    int rowb = (wn * 64 + col) * DDIM;

    // A fragment base: row = iBase + wm*64 + mt*16 + col, k-bytes quad*32 + ks*128.
    const unsigned char* aBase = zn8 + (size_t)(iBase + wm * 64 + col) * DDIM + quad * 32;

    float rs[4][4];
    #pragma unroll
    for (int mt = 0; mt < 4; mt++)
        #pragma unroll
        for (int r = 0; r < 4; r++) rs[mt][r] = 0.f;

    for (int jj = 0; jj < JITERS; jj++) {
        if (jj) __syncthreads();
        const unsigned char* g = gB + (size_t)jj * 128 * DDIM;
        #pragma unroll
        for (int s = 0; s < 8; s++)
            load_lds16(g + s * 16 * DDIM, lB + s * 4096);
        __syncthreads();

        int jt = jBase0 + jj * 128;
        #pragma unroll
        for (int half = 0; half < 2; half++) {
            // load B-frags for nt = half*2, half*2+1 (32 VGPRs live)
            i32x8 bfr[2][2];
            #pragma unroll
            for (int n2 = 0; n2 < 2; n2++) {
                const unsigned char* bbase = sB + rowb + (half * 2 + n2) * 16 * DDIM;
                i32x4 l0 = *(const i32x4*)(bbase + po[0]);
                i32x4 h0 = *(const i32x4*)(bbase + po[1]);
                i32x4 l1 = *(const i32x4*)(bbase + po[2]);
                i32x4 h1 = *(const i32x4*)(bbase + po[3]);
                bfr[n2][0] = __builtin_shufflevector(l0, h0, 0, 1, 2, 3, 4, 5, 6, 7);
                bfr[n2][1] = __builtin_shufflevector(l1, h1, 0, 1, 2, 3, 4, 5, 6, 7);
            }
            #pragma unroll
            for (int mt = 0; mt < 4; mt++) {
                const unsigned char* ap = aBase + mt * 16 * DDIM;
                i32x8 af0 = *(const i32x8*)(ap);
                i32x8 af1 = *(const i32x8*)(ap + 128);
                #pragma unroll
                for (int n2 = 0; n2 < 2; n2++) {
                    int nt = half * 2 + n2;
                    f32x4 acc = {0.f, 0.f, 0.f, 0.f};
                    acc = __builtin_amdgcn_mfma_scale_f32_16x16x128_f8f6f4(
                              af0, bfr[n2][0], acc, 0, 0, 0, SCALE1, 0, SCALE1);
                    acc = __builtin_amdgcn_mfma_scale_f32_16x16x128_f8f6f4(
                              af1, bfr[n2][1], acc, 0, 0, 0, SCALE1, 0, SCALE1);
                    bool dtile = (iBase + wm * 64 + mt * 16) == (jt + wn * 64 + nt * 16);
                    if (dtile) {
                        #pragma unroll
                        for (int r = 0; r < 4; r++) {
                            float e = __expf(2.0f * acc[r]);
                            rs[mt][r] += (quad * 4 + r == col) ? 0.f : e;
                        }
                    } else {
                        #pragma unroll
                        for (int r = 0; r < 4; r++)
                            rs[mt][r] += __expf(2.0f * acc[r]);
                    }
                }
            }
        }
    }

    // reduce over 16 column-lanes, combine wn pair via LDS, one atomic per row.
    #pragma unroll
    for (int mt = 0; mt < 4; mt++)
        #pragma unroll
        for (int r = 0; r < 4; r++) {
            float x = rs[mt][r];
            x += __shfl_xor(x, 1);
            x += __shfl_xor(x, 2);
            x += __shfl_xor(x, 4);
            x += __shfl_xor(x, 8);
            rs[mt][r] = x;
        }
    __syncthreads();
    float* red = (float*)sB;
    if (col == 0) {
        #pragma unroll
        for (int mt = 0; mt < 4; mt++)
            #pragma unroll
            for (int r = 0; r < 4; r++)
                red[wn * 128 + wm * 64 + mt * 16 + quad * 4 + r] = rs[mt][r];
    }
    __syncthreads();
    if (t < 128)
        atomicAdd(&denom[iBase + t], red[t] + red[128 + t]);
}

// Kernel 3: final reduction, 32 blocks, atomic into zeroed out[0].
__global__ __launch_bounds__(256) void loss_kernel(const float* __restrict__ posPart,
                                                   const float* __restrict__ denom,
                                                   float* __restrict__ out) {
    __shared__ float sdata[4];
    int t = threadIdx.x;
    float s = __logf(denom[blockIdx.x * 256 + t]);
    if (t < 32) s -= 2.0f * posPart[blockIdx.x * 32 + t];
    #pragma unroll
    for (int off = 32; off; off >>= 1) s += __shfl_xor(s, off);
    if ((t & 63) == 0) sdata[t >> 6] = s;
    __syncthreads();
    if (t == 0)
        atomicAdd(out, (sdata[0] + sdata[1] + sdata[2] + sdata[3]) * (1.0f / NROWS));
}

extern "C" void kernel_launch(void* const* d_in, const int* in_sizes, int n_in,
                              void* d_out, int out_size, void* d_ws, size_t ws_size,
                              hipStream_t stream) {
    const float* z1 = (const float*)d_in[0];
    const float* z2 = (const float*)d_in[1];

    // ws: zn8 fp8 [8192*256] (2 MB) | denom f32[8192] | posPart f32[1024]
    unsigned char* zn8 = (unsigned char*)d_ws;
    float* denom   = (float*)((char*)d_ws + (size_t)NROWS * DDIM);
    float* posPart = denom + NROWS;

    hipMemsetAsync(d_out, 0, sizeof(float), stream);
    prep_kernel<<<BHALF / 4, 256, 0, stream>>>(z1, z2, zn8, posPart, denom);
    denom_kernel<<<dim3(NROWS / (128 * JITERS), NROWS / 128), 256, 0, stream>>>(zn8, denom);
    loss_kernel<<<NROWS / 256, 256, 0, stream>>>(posPart, denom, (float*)d_out);
}

// Round 6
// 106.396 us; speedup vs baseline: 3.1339x; 3.1339x over previous
//
#include <hip/hip_runtime.h>
#include <hip/hip_bf16.h>

// SimCLR NT-Xent loss. B=4096, D=256, N=2B=8192 rows.
// loss = (1/N) sum_i [ log(denom_i) - log(pos_i) ]
//   denom_i = sum_{j!=i} exp(2*sim_ij),  pos_i = cos(z_i, z_{i+-B}) (fp32 path)
//
// R6 = R5 core minus the fused last-block reduction (suspected cause of the
// R5 harness abort). fp8(e4m3) scaled-MFMA K=128 (numerics verified R3/R4:
// absmax 0.0). ONE barrier-pair per block: full K=256 A+B tiles staged into
// 64 KB LDS via global_load_lds, then 32 MFMAs from ds_read_b128 fragments,
// exp row-sum epilogue, 128 atomics. Separate tiny loss kernel (R4 shape).

#define NROWS 8192
#define BHALF 4096
#define DDIM  256

typedef __attribute__((ext_vector_type(4))) int   i32x4;
typedef __attribute__((ext_vector_type(8))) int   i32x8;
typedef __attribute__((ext_vector_type(4))) float f32x4;

#define SCALE1 0x7F7F7F7F               // e8m0 biased-127 = 2^0 in every byte
#define TWO_LOG2E 2.8853900817779268f   // 2/ln(2): exp(2x) = exp2(x*TWO_LOG2E)

__device__ __forceinline__ void load_lds16(const unsigned char* g, unsigned char* l) {
    __builtin_amdgcn_global_load_lds(
        (const __attribute__((address_space(1))) void*)g,
        (__attribute__((address_space(3))) void*)l, 16, 0, 0);
}

// Kernel 1: norms + fp8-normalized matrix + positive-pair log partials + denom=0.
__global__ __launch_bounds__(256) void prep_kernel(const float* __restrict__ z1,
                                                   const float* __restrict__ z2,
                                                   unsigned char* __restrict__ zn8,
                                                   float* __restrict__ posPart,
                                                   float* __restrict__ denom) {
    __shared__ float sp[4];
    int wave = threadIdx.x >> 6;
    int lane = threadIdx.x & 63;
    int i    = blockIdx.x * 4 + wave;
    float4 a = reinterpret_cast<const float4*>(z1 + (size_t)i * DDIM)[lane];
    float4 b = reinterpret_cast<const float4*>(z2 + (size_t)i * DDIM)[lane];
    float ss1 = a.x * a.x + a.y * a.y + a.z * a.z + a.w * a.w;
    float ss2 = b.x * b.x + b.y * b.y + b.z * b.z + b.w * b.w;
    float dd  = a.x * b.x + a.y * b.y + a.z * b.z + a.w * b.w;
    #pragma unroll
    for (int off = 32; off; off >>= 1) {
        ss1 += __shfl_xor(ss1, off);
        ss2 += __shfl_xor(ss2, off);
        dd  += __shfl_xor(dd, off);
    }
    float n1 = fmaxf(sqrtf(ss1), 1e-8f);
    float n2 = fmaxf(sqrtf(ss2), 1e-8f);
    float i1 = 1.0f / n1, i2 = 1.0f / n2;
    int pa = __builtin_amdgcn_cvt_pk_fp8_f32(a.x * i1, a.y * i1, 0, 0);
    pa     = __builtin_amdgcn_cvt_pk_fp8_f32(a.z * i1, a.w * i1, pa, 1);
    int pb = __builtin_amdgcn_cvt_pk_fp8_f32(b.x * i2, b.y * i2, 0, 0);
    pb     = __builtin_amdgcn_cvt_pk_fp8_f32(b.z * i2, b.w * i2, pb, 1);
    reinterpret_cast<int*>(zn8 + (size_t)i * DDIM)[lane] = pa;
    reinterpret_cast<int*>(zn8 + (size_t)(i + BHALF) * DDIM)[lane] = pb;
    if (lane == 0) sp[wave] = __logf(dd * i1 * i2);
    if (threadIdx.x < 8) denom[blockIdx.x * 8 + threadIdx.x] = 0.0f;
    __syncthreads();
    if (threadIdx.x == 0)
        posPart[blockIdx.x] = sp[0] + sp[1] + sp[2] + sp[3];
}

// Kernel 2: fp8 MFMA sim-GEMM + exp row-sum, one barrier-pair per block.
// 128x128 C-tile, waves 2x2, K=256 = 2 chained 16x16x128 scaled MFMAs.
// LDS: sA/sB 32 KB each; 16-B granules; slot (row, pos) holds k-chunk
// pos^(row&15) -> staging stays lane-contiguous for global_load_lds AND
// fragment ds_read_b128 is 2-way bank-aliased (free, m136).
__global__ __launch_bounds__(256, 2) void denom_kernel(const unsigned char* __restrict__ zn8,
                                                       float* __restrict__ denom) {
    __shared__ __align__(16) unsigned char sA[128 * DDIM];   // 32 KB
    __shared__ __align__(16) unsigned char sB[128 * DDIM];   // 32 KB

    int t    = threadIdx.x;
    int lane = t & 63;
    int wave = t >> 6;
    int col  = lane & 15;
    int quad = lane >> 4;
    int wm = wave >> 1, wn = wave & 1;
    int iBase = blockIdx.y * 128;
    int jBase = blockIdx.x * 128;

    // ---- stage full K=256 of A and B tiles (granule id = s*256 + t) ----
    int rowL  = t >> 4;                 // row = s*16 + rowL; row&15 == rowL
    int chunk = (t & 15) ^ rowL;        // slot pos (t&15) holds chunk (t&15)^rowL
    const unsigned char* gA = zn8 + (size_t)(iBase + rowL) * DDIM + chunk * 16;
    const unsigned char* gB = zn8 + (size_t)(jBase + rowL) * DDIM + chunk * 16;
    unsigned char* lA = sA + t * 16;
    unsigned char* lB = sB + t * 16;
    #pragma unroll
    for (int s = 0; s < 8; s++) {
        load_lds16(gA + s * 4096, lA + s * 4096);
        load_lds16(gB + s * 4096, lB + s * 4096);
    }
    __syncthreads();

    // ---- B fragments: row = wn*64+nt*16+col (row&15==col); granule
    //      g = ks*8 + quad*2 + b lives at pos g^col ----
    i32x8 bfr[4][2];
    {
        const unsigned char* bRow = sB + (size_t)(wn * 64 + col) * DDIM;
        #pragma unroll
        for (int nt = 0; nt < 4; nt++) {
            #pragma unroll
            for (int ks = 0; ks < 2; ks++) {
                int g0 = ks * 8 + quad * 2;
                i32x4 lo = *(const i32x4*)(bRow + nt * 16 * DDIM + ((g0    ) ^ col) * 16);
                i32x4 hi = *(const i32x4*)(bRow + nt * 16 * DDIM + ((g0 + 1) ^ col) * 16);
                bfr[nt][ks] = __builtin_shufflevector(lo, hi, 0, 1, 2, 3, 4, 5, 6, 7);
            }
        }
    }

    float rs[4][4];
    #pragma unroll
    for (int mt = 0; mt < 4; mt++)
        #pragma unroll
        for (int r = 0; r < 4; r++) rs[mt][r] = 0.f;

    const unsigned char* aRow = sA + (size_t)(wm * 64 + col) * DDIM;
    #pragma unroll
    for (int mt = 0; mt < 4; mt++) {
        i32x8 af[2];
        #pragma unroll
        for (int ks = 0; ks < 2; ks++) {
            int g0 = ks * 8 + quad * 2;
            i32x4 lo = *(const i32x4*)(aRow + mt * 16 * DDIM + ((g0    ) ^ col) * 16);
            i32x4 hi = *(const i32x4*)(aRow + mt * 16 * DDIM + ((g0 + 1) ^ col) * 16);
            af[ks] = __builtin_shufflevector(lo, hi, 0, 1, 2, 3, 4, 5, 6, 7);
        }
        int gi = iBase + wm * 64 + mt * 16;
        #pragma unroll
        for (int nt = 0; nt < 4; nt++) {
            f32x4 acc = {0.f, 0.f, 0.f, 0.f};
            acc = __builtin_amdgcn_mfma_scale_f32_16x16x128_f8f6f4(
                      af[0], bfr[nt][0], acc, 0, 0, 0, SCALE1, 0, SCALE1);
            acc = __builtin_amdgcn_mfma_scale_f32_16x16x128_f8f6f4(
                      af[1], bfr[nt][1], acc, 0, 0, 0, SCALE1, 0, SCALE1);
            bool dtile = (gi == jBase + wn * 64 + nt * 16);
            #pragma unroll
            for (int r = 0; r < 4; r++) {
                float e = exp2f(acc[r] * TWO_LOG2E);
                if (dtile && (quad * 4 + r) == col) e = 0.f;
                rs[mt][r] += e;
            }
        }
    }

    // ---- reduce 16 column-lanes, combine wn pair via LDS, 128 atomics ----
    #pragma unroll
    for (int mt = 0; mt < 4; mt++)
        #pragma unroll
        for (int r = 0; r < 4; r++) {
            float x = rs[mt][r];
            x += __shfl_xor(x, 1);
            x += __shfl_xor(x, 2);
            x += __shfl_xor(x, 4);
            x += __shfl_xor(x, 8);
            rs[mt][r] = x;
        }
    __syncthreads();                     // sA tile no longer needed
    float* red = (float*)sA;
    if (col == 0) {
        #pragma unroll
        for (int mt = 0; mt < 4; mt++)
            #pragma unroll
            for (int r = 0; r < 4; r++)
                red[wn * 128 + wm * 64 + mt * 16 + quad * 4 + r] = rs[mt][r];
    }
    __syncthreads();
    if (t < 128)
        atomicAdd(&denom[iBase + t], red[t] + red[128 + t]);
}

// Kernel 3: final reduction, 32 blocks, atomic into zeroed out[0].
__global__ __launch_bounds__(256) void loss_kernel(const float* __restrict__ posPart,
                                                   const float* __restrict__ denom,
                                                   float* __restrict__ out) {
    __shared__ float sdata[4];
    int t = threadIdx.x;
    float s = __logf(denom[blockIdx.x * 256 + t]);
    if (t < 32) s -= 2.0f * posPart[blockIdx.x * 32 + t];
    #pragma unroll
    for (int off = 32; off; off >>= 1) s += __shfl_xor(s, off);
    if ((t & 63) == 0) sdata[t >> 6] = s;
    __syncthreads();
    if (t == 0)
        atomicAdd(out, (sdata[0] + sdata[1] + sdata[2] + sdata[3]) * (1.0f / NROWS));
}

extern "C" void kernel_launch(void* const* d_in, const int* in_sizes, int n_in,
                              void* d_out, int out_size, void* d_ws, size_t ws_size,
                              hipStream_t stream) {
    const float* z1 = (const float*)d_in[0];
    const float* z2 = (const float*)d_in[1];

    // ws: zn8 fp8 [8192*256] (2 MB) | denom f32[8192] | posPart f32[1024]
    unsigned char* zn8 = (unsigned char*)d_ws;
    float* denom   = (float*)((char*)d_ws + (size_t)NROWS * DDIM);
    float* posPart = denom + NROWS;

    hipMemsetAsync(d_out, 0, sizeof(float), stream);
    prep_kernel<<<BHALF / 4, 256, 0, stream>>>(z1, z2, zn8, posPart, denom);
    denom_kernel<<<dim3(NROWS / 128, NROWS / 128), 256, 0, stream>>>(zn8, denom);
    loss_kernel<<<NROWS / 256, 256, 0, stream>>>(posPart, denom, (float*)d_out);
}

// Round 7
// 89.266 us; speedup vs baseline: 3.7353x; 1.1919x over previous
//
#include <hip/hip_runtime.h>
#include <hip/hip_bf16.h>

// SimCLR NT-Xent loss. B=4096, D=256, N=2B=8192 rows.
// loss = (1/N) sum_i [ log(denom_i) - log(pos_i) ]
//   denom_i = sum_{j!=i} exp(2*sim_ij),  pos_i = cos(z_i, z_{i+-B}) (fp32 path)
//
// R7 = R6 + symmetry: sim is symmetric, so only upper-triangular 128x128
// tiles are computed (2080 of 4096 blocks; exact 65x32-grid bijection).
// Off-diag tiles emit row-sums to denom[i] AND col-sums to denom[j];
// diag tiles keep the verified masked row-sum path. Halves MFMA/exp/LDS/
// staging. Memset dispatch dropped (prep zeroes d_out).

#define NROWS 8192
#define BHALF 4096
#define DDIM  256

typedef __attribute__((ext_vector_type(4))) int   i32x4;
typedef __attribute__((ext_vector_type(8))) int   i32x8;
typedef __attribute__((ext_vector_type(4))) float f32x4;

#define SCALE1 0x7F7F7F7F               // e8m0 biased-127 = 2^0 in every byte
#define TWO_LOG2E 2.8853900817779268f   // 2/ln(2): exp(2x) = exp2(x*TWO_LOG2E)

__device__ __forceinline__ void load_lds16(const unsigned char* g, unsigned char* l) {
    __builtin_amdgcn_global_load_lds(
        (const __attribute__((address_space(1))) void*)g,
        (__attribute__((address_space(3))) void*)l, 16, 0, 0);
}

// Kernel 1: norms + fp8-normalized matrix + positive-pair log partials +
// denom zero-init + out zero-init.
__global__ __launch_bounds__(256) void prep_kernel(const float* __restrict__ z1,
                                                   const float* __restrict__ z2,
                                                   unsigned char* __restrict__ zn8,
                                                   float* __restrict__ posPart,
                                                   float* __restrict__ denom,
                                                   float* __restrict__ out) {
    __shared__ float sp[4];
    int wave = threadIdx.x >> 6;
    int lane = threadIdx.x & 63;
    int i    = blockIdx.x * 4 + wave;
    float4 a = reinterpret_cast<const float4*>(z1 + (size_t)i * DDIM)[lane];
    float4 b = reinterpret_cast<const float4*>(z2 + (size_t)i * DDIM)[lane];
    float ss1 = a.x * a.x + a.y * a.y + a.z * a.z + a.w * a.w;
    float ss2 = b.x * b.x + b.y * b.y + b.z * b.z + b.w * b.w;
    float dd  = a.x * b.x + a.y * b.y + a.z * b.z + a.w * b.w;
    #pragma unroll
    for (int off = 32; off; off >>= 1) {
        ss1 += __shfl_xor(ss1, off);
        ss2 += __shfl_xor(ss2, off);
        dd  += __shfl_xor(dd, off);
    }
    float n1 = fmaxf(sqrtf(ss1), 1e-8f);
    float n2 = fmaxf(sqrtf(ss2), 1e-8f);
    float i1 = 1.0f / n1, i2 = 1.0f / n2;
    int pa = __builtin_amdgcn_cvt_pk_fp8_f32(a.x * i1, a.y * i1, 0, 0);
    pa     = __builtin_amdgcn_cvt_pk_fp8_f32(a.z * i1, a.w * i1, pa, 1);
    int pb = __builtin_amdgcn_cvt_pk_fp8_f32(b.x * i2, b.y * i2, 0, 0);
    pb     = __builtin_amdgcn_cvt_pk_fp8_f32(b.z * i2, b.w * i2, pb, 1);
    reinterpret_cast<int*>(zn8 + (size_t)i * DDIM)[lane] = pa;
    reinterpret_cast<int*>(zn8 + (size_t)(i + BHALF) * DDIM)[lane] = pb;
    if (lane == 0) sp[wave] = __logf(dd * i1 * i2);
    if (threadIdx.x < 8) denom[blockIdx.x * 8 + threadIdx.x] = 0.0f;
    if (blockIdx.x == 0 && threadIdx.x == 64) out[0] = 0.0f;
    __syncthreads();
    if (threadIdx.x == 0)
        posPart[blockIdx.x] = sp[0] + sp[1] + sp[2] + sp[3];
}

// Kernel 2: fp8 MFMA sim-GEMM + exp row/col-sums, upper-triangular tiles only.
// 128x128 C-tile, waves 2x2, K=256 = 2 chained 16x16x128 scaled MFMAs, one
// barrier-pair. LDS 16-B-granule XOR swizzle (verified R6, 0 conflicts).
__global__ __launch_bounds__(256, 2) void denom_kernel(const unsigned char* __restrict__ zn8,
                                                       float* __restrict__ denom) {
    __shared__ __align__(16) unsigned char sA[128 * DDIM];   // 32 KB
    __shared__ __align__(16) unsigned char sB[128 * DDIM];   // 32 KB

    // triangular decode: 65x32 grid -> {(bi,bj) : 0 <= bi <= bj < 64}
    int x = blockIdx.x, y = blockIdx.y;
    int bi, bj;
    if (x > y) { bi = y;      bj = x - 1;  }
    else       { bi = 63 - y; bj = 63 - x; }
    int iBase = bi * 128;
    int jBase = bj * 128;
    bool isDiag = (bi == bj);

    int t    = threadIdx.x;
    int lane = t & 63;
    int wave = t >> 6;
    int col  = lane & 15;
    int quad = lane >> 4;
    int wm = wave >> 1, wn = wave & 1;

    // ---- stage full K=256 of A and B tiles (granule id = s*256 + t) ----
    int rowL  = t >> 4;                 // row = s*16 + rowL; row&15 == rowL
    int chunk = (t & 15) ^ rowL;        // slot pos (t&15) holds chunk (t&15)^rowL
    const unsigned char* gA = zn8 + (size_t)(iBase + rowL) * DDIM + chunk * 16;
    const unsigned char* gB = zn8 + (size_t)(jBase + rowL) * DDIM + chunk * 16;
    unsigned char* lA = sA + t * 16;
    unsigned char* lB = sB + t * 16;
    #pragma unroll
    for (int s = 0; s < 8; s++) {
        load_lds16(gA + s * 4096, lA + s * 4096);
        load_lds16(gB + s * 4096, lB + s * 4096);
    }
    __syncthreads();

    // ---- B fragments: row = wn*64+nt*16+col; granule g = ks*8+quad*2+b at pos g^col
    i32x8 bfr[4][2];
    {
        const unsigned char* bRow = sB + (size_t)(wn * 64 + col) * DDIM;
        #pragma unroll
        for (int nt = 0; nt < 4; nt++) {
            #pragma unroll
            for (int ks = 0; ks < 2; ks++) {
                int g0 = ks * 8 + quad * 2;
                i32x4 lo = *(const i32x4*)(bRow + nt * 16 * DDIM + ((g0    ) ^ col) * 16);
                i32x4 hi = *(const i32x4*)(bRow + nt * 16 * DDIM + ((g0 + 1) ^ col) * 16);
                bfr[nt][ks] = __builtin_shufflevector(lo, hi, 0, 1, 2, 3, 4, 5, 6, 7);
            }
        }
    }

    float rs[4][4];                     // row-sums: [mt][r]
    float cs[4] = {0.f, 0.f, 0.f, 0.f}; // col-sums: [nt]
    #pragma unroll
    for (int mt = 0; mt < 4; mt++)
        #pragma unroll
        for (int r = 0; r < 4; r++) rs[mt][r] = 0.f;

    const unsigned char* aRow = sA + (size_t)(wm * 64 + col) * DDIM;
    #pragma unroll
    for (int mt = 0; mt < 4; mt++) {
        i32x8 af[2];
        #pragma unroll
        for (int ks = 0; ks < 2; ks++) {
            int g0 = ks * 8 + quad * 2;
            i32x4 lo = *(const i32x4*)(aRow + mt * 16 * DDIM + ((g0    ) ^ col) * 16);
            i32x4 hi = *(const i32x4*)(aRow + mt * 16 * DDIM + ((g0 + 1) ^ col) * 16);
            af[ks] = __builtin_shufflevector(lo, hi, 0, 1, 2, 3, 4, 5, 6, 7);
        }
        int gi = iBase + wm * 64 + mt * 16;
        #pragma unroll
        for (int nt = 0; nt < 4; nt++) {
            f32x4 acc = {0.f, 0.f, 0.f, 0.f};
            acc = __builtin_amdgcn_mfma_scale_f32_16x16x128_f8f6f4(
                      af[0], bfr[nt][0], acc, 0, 0, 0, SCALE1, 0, SCALE1);
            acc = __builtin_amdgcn_mfma_scale_f32_16x16x128_f8f6f4(
                      af[1], bfr[nt][1], acc, 0, 0, 0, SCALE1, 0, SCALE1);
            bool dtile = (gi == jBase + wn * 64 + nt * 16);
            float csl = 0.f;
            #pragma unroll
            for (int r = 0; r < 4; r++) {
                float e = exp2f(acc[r] * TWO_LOG2E);
                if (dtile && (quad * 4 + r) == col) e = 0.f;
                rs[mt][r] += e;
                csl += e;
            }
            cs[nt] += csl;
        }
    }

    // ---- col-sums (off-diag only): reduce across quads, atomics to denom[j] ----
    if (!isDiag) {
        #pragma unroll
        for (int nt = 0; nt < 4; nt++) {
            float v = cs[nt];
            v += __shfl_xor(v, 16);
            v += __shfl_xor(v, 32);
            if (quad == 0)
                atomicAdd(&denom[jBase + wn * 64 + nt * 16 + col], v);
        }
    }

    // ---- row-sums: reduce 16 column-lanes, combine wn pair via LDS, 128 atomics ----
    #pragma unroll
    for (int mt = 0; mt < 4; mt++)
        #pragma unroll
        for (int r = 0; r < 4; r++) {
            float v = rs[mt][r];
            v += __shfl_xor(v, 1);
            v += __shfl_xor(v, 2);
            v += __shfl_xor(v, 4);
            v += __shfl_xor(v, 8);
            rs[mt][r] = v;
        }
    __syncthreads();                     // sA tile no longer needed
    float* red = (float*)sA;
    if (col == 0) {
        #pragma unroll
        for (int mt = 0; mt < 4; mt++)
            #pragma unroll
            for (int r = 0; r < 4; r++)
                red[wn * 128 + wm * 64 + mt * 16 + quad * 4 + r] = rs[mt][r];
    }
    __syncthreads();
    if (t < 128)
        atomicAdd(&denom[iBase + t], red[t] + red[128 + t]);
}

// Kernel 3: final reduction, 32 blocks, atomic into prep-zeroed out[0].
__global__ __launch_bounds__(256) void loss_kernel(const float* __restrict__ posPart,
                                                   const float* __restrict__ denom,
                                                   float* __restrict__ out) {
    __shared__ float sdata[4];
    int t = threadIdx.x;
    float s = __logf(denom[blockIdx.x * 256 + t]);
    if (t < 32) s -= 2.0f * posPart[blockIdx.x * 32 + t];
    #pragma unroll
    for (int off = 32; off; off >>= 1) s += __shfl_xor(s, off);
    if ((t & 63) == 0) sdata[t >> 6] = s;
    __syncthreads();
    if (t == 0)
        atomicAdd(out, (sdata[0] + sdata[1] + sdata[2] + sdata[3]) * (1.0f / NROWS));
}

extern "C" void kernel_launch(void* const* d_in, const int* in_sizes, int n_in,
                              void* d_out, int out_size, void* d_ws, size_t ws_size,
                              hipStream_t stream) {
    const float* z1 = (const float*)d_in[0];
    const float* z2 = (const float*)d_in[1];

    // ws: zn8 fp8 [8192*256] (2 MB) | denom f32[8192] | posPart f32[1024]
    unsigned char* zn8 = (unsigned char*)d_ws;
    float* denom   = (float*)((char*)d_ws + (size_t)NROWS * DDIM);
    float* posPart = denom + NROWS;

    prep_kernel<<<BHALF / 4, 256, 0, stream>>>(z1, z2, zn8, posPart, denom, (float*)d_out);
    denom_kernel<<<dim3(65, 32), 256, 0, stream>>>(zn8, denom);
    loss_kernel<<<NROWS / 256, 256, 0, stream>>>(posPart, denom, (float*)d_out);
}